// Round 10
// baseline (920.830 us; speedup 1.0000x reference)
//
#include <hip/hip_runtime.h>
#include <hip/hip_bf16.h>

// VectorQuantize: argmin_k ||x - e_k||^2 then gather values[k].
// R10: barrier-free streaming GEMM. A-tile (128x512 bf16 = 128 KB) resident in
// LDS (loaded once, one barrier); each of 8 waves independently streams its
// private 512-code strip of B global->VGPR (NO LDS staging, NO gload_lds, NO
// K-loop barriers) with 1-step b-prefetch. Operand packs live in d_out (not
// d_ws) -- R2-R9 all staged from d_ws behind per-step barriers and pinned at
// ~2 B/cyc/CU; this removes both suspects at once. Epilogue: running per-row
// top-2 keys per wave (16 records/row) -> global top-4 -> exact f32 rescore
// (np tie semantics) -> gather values[best].
//
// Pack layouts (granule = 8 bf16 = 16 B):
//   Apack[128 tiles][k16 0..63][row 0..127][8]   (16 MB, in d_out)
//   Bpack[k16 0..63][code 0..8191][8]            (8 MB, in d_out + 16 MB)

#define D      512
#define M      16384
#define NCODE  8192
#define KSTEPS 16          // K=512 / 32
#define NCH    16          // chunks per wave (512 codes / 32)

typedef float f32x4  __attribute__((ext_vector_type(4)));
typedef short bf16x8 __attribute__((ext_vector_type(8)));

#define KMAX 0xFFFFFFFFFFFFFFFFull

__device__ __forceinline__ unsigned long long score_key(float sc, int code) {
  unsigned int u = __float_as_uint(sc);
  unsigned int su = u ^ ((unsigned int)((int)u >> 31) | 0x80000000u);
  return ((unsigned long long)su << 32) | (unsigned int)code;
}

__device__ __forceinline__ void kins2(unsigned long long k,
                                      unsigned long long& k1, unsigned long long& k2) {
  if (k < k1) { k2 = k1; k1 = k; }
  else if (k < k2) { k2 = k; }
}

__device__ __forceinline__ void kins4(unsigned long long k,
    unsigned long long& k0, unsigned long long& k1,
    unsigned long long& k2, unsigned long long& k3) {
  if (k < k0)      { k3 = k2; k2 = k1; k1 = k0; k0 = k; }
  else if (k < k1) { k3 = k2; k2 = k1; k1 = k; }
  else if (k < k2) { k3 = k2; k2 = k; }
  else if (k < k3) { k3 = k; }
}

// ---- 1a. f32 -> hi-bf16 128-row tile-transposed pack (A) --------------------
__global__ __launch_bounds__(256)
void prep_tile(const float* __restrict__ src, __hip_bfloat16* __restrict__ dst) {
  __shared__ __hip_bfloat16 tile[128][136];
  const int tid = threadIdx.x;
  const float* srow = src + (size_t)blockIdx.x * 128 * D;
  __hip_bfloat16* dbase = dst + (size_t)blockIdx.x * 65536;

#pragma unroll 1
  for (int c = 0; c < 4; ++c) {
    __syncthreads();
#pragma unroll
    for (int j = 0; j < 8; ++j) {
      int f = tid + j * 256;               // k16l = f&15, row = f>>4
      int row = f >> 4, k16l = f & 15;
      const float4* p = (const float4*)(srow + (size_t)row * D + c * 128 + k16l * 8);
      float4 v0 = p[0], v1 = p[1];
      float vv[8] = {v0.x, v0.y, v0.z, v0.w, v1.x, v1.y, v1.z, v1.w};
      union { bf16x8 v; unsigned short u[8]; } pk;
#pragma unroll
      for (int e = 0; e < 8; ++e) {
        __hip_bfloat16 h = __float2bfloat16(vv[e]);   // RNE
        pk.u[e] = *(unsigned short*)&h;
      }
      *(bf16x8*)&tile[row][k16l * 8] = pk.v;
    }
    __syncthreads();
#pragma unroll
    for (int j = 0; j < 8; ++j) {
      int g = tid + j * 256;               // row = g&127, k16l = g>>7
      int row = g & 127, k16l = g >> 7;
      bf16x8 v = *(const bf16x8*)&tile[row][k16l * 8];
      *(bf16x8*)(dbase + ((size_t)(c * 16 + k16l) * 128 + row) * 8) = v;
    }
  }
}

// ---- 1b. f32 -> hi-bf16 full-width K-major pack (B) -------------------------
// dst granule = k16 * 8192 + code. Block t handles codes t*128..t*128+127.
__global__ __launch_bounds__(256)
void prep_bstream(const float* __restrict__ src, __hip_bfloat16* __restrict__ dst) {
  __shared__ __hip_bfloat16 tile[128][136];
  const int tid = threadIdx.x;
  const int t = blockIdx.x;
  const float* srow = src + (size_t)t * 128 * D;

#pragma unroll 1
  for (int c = 0; c < 4; ++c) {
    __syncthreads();
#pragma unroll
    for (int j = 0; j < 8; ++j) {
      int f = tid + j * 256;
      int row = f >> 4, k16l = f & 15;
      const float4* p = (const float4*)(srow + (size_t)row * D + c * 128 + k16l * 8);
      float4 v0 = p[0], v1 = p[1];
      float vv[8] = {v0.x, v0.y, v0.z, v0.w, v1.x, v1.y, v1.z, v1.w};
      union { bf16x8 v; unsigned short u[8]; } pk;
#pragma unroll
      for (int e = 0; e < 8; ++e) {
        __hip_bfloat16 h = __float2bfloat16(vv[e]);
        pk.u[e] = *(unsigned short*)&h;
      }
      *(bf16x8*)&tile[row][k16l * 8] = pk.v;
    }
    __syncthreads();
#pragma unroll
    for (int j = 0; j < 8; ++j) {
      int g = tid + j * 256;               // row (code-local) = g&127, k16l = g>>7
      int row = g & 127, k16l = g >> 7;
      bf16x8 v = *(const bf16x8*)&tile[row][k16l * 8];
      *(bf16x8*)(dst + (((size_t)(c * 16 + k16l) * NCODE) + t * 128 + row) * 8) = v;
    }
  }
}

// ---- 2. exact f32 row sum-of-squares (codebook) -----------------------------
__global__ __launch_bounds__(256)
void rowsumsq(const float* __restrict__ src, float* __restrict__ dst, int nrows) {
  int gw = (blockIdx.x * 256 + threadIdx.x) >> 6;
  if (gw >= nrows) return;
  int lane = threadIdx.x & 63;
  const float4* s4 = (const float4*)(src + (size_t)gw * D);
  float s = 0.f;
#pragma unroll
  for (int i = 0; i < 2; ++i) {
    float4 v = s4[lane + i * 64];
    s += v.x * v.x + v.y * v.y + v.z * v.z + v.w * v.w;
  }
#pragma unroll
  for (int off = 32; off > 0; off >>= 1) s += __shfl_down(s, off, 64);
  if (lane == 0) dst[gw] = s;
}

// ---- 3. barrier-free streaming GEMM + fused running top-2 -------------------
// 256 blocks (1/CU): block = (mt, ch). 512 thr = 8 waves; wave w streams codes
// ch*4096 + w*512 .. +511 in 16 chunks of 32. Swapped mfma(b, a):
// acc[nc][m][q] -> code = c0 + nc*16 + lh*4 + q, row = mt*128 + m*16 + lr.
__global__ __launch_bounds__(512, 1)
void vq_stream(const __hip_bfloat16* __restrict__ Apack,
               const __hip_bfloat16* __restrict__ Bpack,
               const float* __restrict__ e_sq,
               ulonglong2* __restrict__ cand2) {
  extern __shared__ __hip_bfloat16 A_l[];   // 8192 granules = 128 KB

  const int tid = threadIdx.x;
  const int w = tid >> 6, l = tid & 63;
  const int lr = l & 15, lh = l >> 4;

  const int bid = blockIdx.x;
  const int xcd = bid & 7, i = bid >> 3;    // 32 blocks per XCD
  const int ch = xcd & 1;                   // one 4-MB B-half per XCD (L2-fit)
  const int mt = (xcd >> 1) * 32 + i;       // 128 m-tiles

  // A prologue: plain loads + LDS write, once; the only barrier in the kernel.
  {
    const float4* src = (const float4*)(Apack + (size_t)mt * 65536);
    float4* dst = (float4*)A_l;
#pragma unroll
    for (int j = 0; j < 16; ++j) dst[tid + j * 512] = src[tid + j * 512];
  }
  __syncthreads();

  const bf16x8* Ag = (const bf16x8*)A_l;
  const int cbase = ch * 4096 + w * 512;

  unsigned long long rk1[8], rk2[8];
#pragma unroll
  for (int m = 0; m < 8; ++m) { rk1[m] = KMAX; rk2[m] = KMAX; }

#pragma unroll 1
  for (int j = 0; j < NCH; ++j) {
    const int c0 = cbase + j * 32;
    f32x4 acc[2][8] = {};

    // b-prefetch for t=0
    bf16x8 nb0 = *(const bf16x8*)(Bpack + ((size_t)lh * NCODE + c0 + lr) * 8);
    bf16x8 nb1 = *(const bf16x8*)(Bpack + ((size_t)lh * NCODE + c0 + 16 + lr) * 8);

#pragma unroll 1
    for (int t = 0; t < KSTEPS; ++t) {
      bf16x8 b0 = nb0, b1 = nb1;
      if (t + 1 < KSTEPS) {
        const size_t kg = (size_t)(4 * (t + 1) + lh) * NCODE;
        nb0 = *(const bf16x8*)(Bpack + (kg + c0 + lr) * 8);
        nb1 = *(const bf16x8*)(Bpack + (kg + c0 + 16 + lr) * 8);
      }
      const int ka = (4 * t + lh) * 128;
      bf16x8 a[8];
#pragma unroll
      for (int m = 0; m < 8; ++m) a[m] = Ag[ka + m * 16 + lr];
#pragma unroll
      for (int m = 0; m < 8; ++m) {
        acc[0][m] = __builtin_amdgcn_mfma_f32_16x16x32_bf16(b0, a[m], acc[0][m], 0, 0, 0);
        acc[1][m] = __builtin_amdgcn_mfma_f32_16x16x32_bf16(b1, a[m], acc[1][m], 0, 0, 0);
      }
    }

    // chunk epilogue: scores -> per-row top-2, folded into running keys
    float4 es0 = *(const float4*)&e_sq[c0 + lh * 4];
    float4 es1 = *(const float4*)&e_sq[c0 + 16 + lh * 4];
    float e0v[4] = {es0.x, es0.y, es0.z, es0.w};
    float e1v[4] = {es1.x, es1.y, es1.z, es1.w};
#pragma unroll
    for (int m = 0; m < 8; ++m) {
      unsigned long long k1 = KMAX, k2 = KMAX;
#pragma unroll
      for (int q = 0; q < 4; ++q) {
        kins2(score_key(e0v[q] - 2.0f * acc[0][m][q], c0 + lh * 4 + q), k1, k2);
        kins2(score_key(e1v[q] - 2.0f * acc[1][m][q], c0 + 16 + lh * 4 + q), k1, k2);
      }
#pragma unroll
      for (int s = 16; s <= 32; s <<= 1) {   // reduce over lh
        unsigned long long o1 = __shfl_xor(k1, s, 64);
        unsigned long long o2 = __shfl_xor(k2, s, 64);
        kins2(o1, k1, k2);
        kins2(o2, k1, k2);
      }
      kins2(k1, rk1[m], rk2[m]);
      kins2(k2, rk1[m], rk2[m]);
    }
  }

  if (lh == 0) {
#pragma unroll
    for (int m = 0; m < 8; ++m) {
      int row = mt * 128 + m * 16 + lr;
      cand2[(size_t)row * 16 + ch * 8 + w] = make_ulonglong2(rk1[m], rk2[m]);
    }
  }
}

// ---- 4. global top-4 over 16 records/row, exact f32 rescore, gather ---------
__global__ __launch_bounds__(256)
void vq_merge16(const float* __restrict__ x, const float* __restrict__ cb,
                const float* __restrict__ values, const float* __restrict__ e_sq,
                const ulonglong2* __restrict__ cand2, float* __restrict__ out) {
  int row = blockIdx.x * 4 + (threadIdx.x >> 6);
  int l = threadIdx.x & 63;

  unsigned long long k0 = KMAX, k1 = KMAX, k2 = KMAX, k3 = KMAX;
  if (l < 16) {
    ulonglong2 e = cand2[(size_t)row * 16 + l];
    kins4(e.x, k0, k1, k2, k3);
    kins4(e.y, k0, k1, k2, k3);
  }
#pragma unroll
  for (int s = 1; s < 64; s <<= 1) {
    unsigned long long o0 = __shfl_xor(k0, s, 64), o1 = __shfl_xor(k1, s, 64);
    unsigned long long o2 = __shfl_xor(k2, s, 64), o3 = __shfl_xor(k3, s, 64);
    kins4(o0, k0, k1, k2, k3); kins4(o1, k0, k1, k2, k3);
    kins4(o2, k0, k1, k2, k3); kins4(o3, k0, k1, k2, k3);
  }
  int i0 = (int)(k0 & 8191), i1 = (int)(k1 & 8191);
  int i2 = (int)(k2 & 8191), i3 = (int)(k3 & 8191);

  // exact f32 rescore (deterministic order)
  const float4* xr = (const float4*)(x + (size_t)row * D);
  const float4* c0 = (const float4*)(cb + (size_t)i0 * D);
  const float4* c1 = (const float4*)(cb + (size_t)i1 * D);
  const float4* c2 = (const float4*)(cb + (size_t)i2 * D);
  const float4* c3 = (const float4*)(cb + (size_t)i3 * D);
  float xsq = 0.f, t0 = 0.f, t1 = 0.f, t2 = 0.f, t3 = 0.f;
#pragma unroll
  for (int u = 0; u < 2; ++u) {
    float4 xv = xr[l + 64 * u];
    float4 a = c0[l + 64 * u], b = c1[l + 64 * u];
    float4 c = c2[l + 64 * u], e = c3[l + 64 * u];
    xsq += xv.x * xv.x + xv.y * xv.y + xv.z * xv.z + xv.w * xv.w;
    t0 += xv.x * a.x + xv.y * a.y + xv.z * a.z + xv.w * a.w;
    t1 += xv.x * b.x + xv.y * b.y + xv.z * b.z + xv.w * b.w;
    t2 += xv.x * c.x + xv.y * c.y + xv.z * c.z + xv.w * c.w;
    t3 += xv.x * e.x + xv.y * e.y + xv.z * e.z + xv.w * e.w;
  }
#pragma unroll
  for (int s = 1; s < 64; s <<= 1) {
    xsq += __shfl_xor(xsq, s, 64);
    t0 += __shfl_xor(t0, s, 64); t1 += __shfl_xor(t1, s, 64);
    t2 += __shfl_xor(t2, s, 64); t3 += __shfl_xor(t3, s, 64);
  }
  float D0 = xsq - 2.0f * t0 + e_sq[i0];
  float D1 = xsq - 2.0f * t1 + e_sq[i1];
  float D2 = xsq - 2.0f * t2 + e_sq[i2];
  float D3 = xsq - 2.0f * t3 + e_sq[i3];
  float bdist = D0; int best = i0;
  if (D1 < bdist || (D1 == bdist && i1 < best)) { bdist = D1; best = i1; }
  if (D2 < bdist || (D2 == bdist && i2 < best)) { bdist = D2; best = i2; }
  if (D3 < bdist || (D3 == bdist && i3 < best)) { bdist = D3; best = i3; }

  const float4* vsrc = (const float4*)(values + (size_t)best * D);
  float4* dst = (float4*)(out + (size_t)row * D);
  dst[l] = vsrc[l];
  dst[l + 64] = vsrc[l + 64];
}

// ============================================================================
extern "C" void kernel_launch(void* const* d_in, const int* in_sizes, int n_in,
                              void* d_out, int out_size, void* d_ws, size_t ws_size,
                              hipStream_t stream) {
  const float* x      = (const float*)d_in[0];
  const float* cb     = (const float*)d_in[1];
  const float* values = (const float*)d_in[2];
  float* out = (float*)d_out;

  // Packs live in d_out (32 MB): A 16 MB + B 8 MB. Overwritten by the final
  // output AFTER the GEMM has consumed them (stream-ordered; merge reads no
  // packs). cand2 + e_sq live in d_ws.
  const size_t A_BYTES = (size_t)M * 512 * 2;         // 16 MB
  __hip_bfloat16* Apack = (__hip_bfloat16*)d_out;
  __hip_bfloat16* Bpack = (__hip_bfloat16*)((char*)d_out + A_BYTES);

  ulonglong2* cand2 = (ulonglong2*)d_ws;              // 16384*16*16 = 4 MB
  float* e_sq = (float*)((char*)d_ws + (size_t)M * 16 * 16);

  const int LDS_GEMM = 131072;   // A-tile 128 KB
  (void)hipFuncSetAttribute(reinterpret_cast<const void*>(vq_stream),
                            hipFuncAttributeMaxDynamicSharedMemorySize, LDS_GEMM);

  prep_tile<<<M / 128, 256, 0, stream>>>(x, Apack);
  prep_bstream<<<NCODE / 128, 256, 0, stream>>>(cb, Bpack);
  rowsumsq<<<NCODE / 4, 256, 0, stream>>>(cb, e_sq, NCODE);
  vq_stream<<<256, 512, LDS_GEMM, stream>>>(Apack, Bpack, e_sq, cand2);
  vq_merge16<<<M / 4, 256, 0, stream>>>(x, cb, values, e_sq, cand2, out);
}

// Round 11
// 799.930 us; speedup vs baseline: 1.1511x; 1.1511x over previous
//
#include <hip/hip_runtime.h>
#include <hip/hip_bf16.h>

// VectorQuantize: argmin_k ||x - e_k||^2 then gather values[k].
// R11 = R7 (256x256-tile BK=64 2-phase GEMM, best measured: 635 us) with
// READER DECORRELATION, nothing else changed:
//   1. diagonal block map (mt = bid&63, ct = (bid>>6 + mt)&31): concurrent
//      blocks spread across all 32 B-tiles (~4 sharers instead of 64),
//   2. per-block K-phase rotation (staged slab u = (t + bid) & 7): the few
//      same-tile sharers read DIFFERENT 32-KB K-slabs at any instant,
//   3. no XCD pinning (it phase-locked same-tile groups).
// R1-R10 invariant: every kernel served operand reads at only ~1.3-2.3 TB/s
// aggregate; hypothesis = same-line TCC-bank hotspot from deliberately
// correlated readers. This round is the direct test.
//
// Pack layout: P[tile256][k16 0..63][row 0..255][8] bf16; K-step t stages
// k16 = 8t..8t+7 (32 KB A + 32 KB B slabs), granule f identical in global
// and LDS -> gload_lds lane-linear. Epilogue: per-wave per-row top-2 keys
// (np tie semantics via sortable u64) -> global top-4 -> exact f32 rescore
// -> gather values[best].

#define D      512
#define M      16384
#define NCODE  8192
#define KH     512
#define NSTEP  8           // K-steps of BK=64
#define TILEG  131072      // elems per 256-row tile (256*512)

typedef float f32x4  __attribute__((ext_vector_type(4)));
typedef short bf16x8 __attribute__((ext_vector_type(8)));

#define KMAX 0xFFFFFFFFFFFFFFFFull

__device__ __forceinline__ void gload16(const __hip_bfloat16* g, __hip_bfloat16* l) {
  __builtin_amdgcn_global_load_lds(
      (const __attribute__((address_space(1))) void*)g,
      (__attribute__((address_space(3))) void*)l, 16, 0, 0);
}

__device__ __forceinline__ unsigned long long score_key(float sc, int code) {
  unsigned int u = __float_as_uint(sc);
  unsigned int su = u ^ ((unsigned int)((int)u >> 31) | 0x80000000u);
  return ((unsigned long long)su << 32) | (unsigned int)code;
}

__device__ __forceinline__ void kins2(unsigned long long k,
                                      unsigned long long& k1, unsigned long long& k2) {
  if (k < k1) { k2 = k1; k1 = k; }
  else if (k < k2) { k2 = k; }
}

__device__ __forceinline__ void kins4(unsigned long long k,
    unsigned long long& k0, unsigned long long& k1,
    unsigned long long& k2, unsigned long long& k3) {
  if (k < k0)      { k3 = k2; k2 = k1; k1 = k0; k0 = k; }
  else if (k < k1) { k3 = k2; k2 = k1; k1 = k; }
  else if (k < k2) { k3 = k2; k2 = k; }
  else if (k < k3) { k3 = k; }
}

// ---- 1. f32 -> hi-bf16 256-row tile-transposed pack -------------------------
__global__ __launch_bounds__(256)
void prep256(const float* __restrict__ src, __hip_bfloat16* __restrict__ dst) {
  __shared__ __hip_bfloat16 tile[256][72];
  const int tid = threadIdx.x;
  const int c = blockIdx.x & 7, t = blockIdx.x >> 3;
  const float* srow = src + (size_t)t * 256 * D;
  __hip_bfloat16* dbase = dst + (size_t)t * TILEG;

#pragma unroll
  for (int j = 0; j < 8; ++j) {
    int f = tid + j * 256;                 // row = f>>3, k16l = f&7
    int row = f >> 3, k16l = f & 7;
    const float4* p = (const float4*)(srow + (size_t)row * D + c * 64 + k16l * 8);
    float4 v0 = p[0], v1 = p[1];
    float vv[8] = {v0.x, v0.y, v0.z, v0.w, v1.x, v1.y, v1.z, v1.w};
    union { bf16x8 v; unsigned short u[8]; } pk;
#pragma unroll
    for (int e = 0; e < 8; ++e) {
      __hip_bfloat16 h = __float2bfloat16(vv[e]);   // RNE
      pk.u[e] = *(unsigned short*)&h;
    }
    *(bf16x8*)&tile[row][k16l * 8] = pk.v;
  }
  __syncthreads();
#pragma unroll
  for (int j = 0; j < 8; ++j) {
    int g = tid + j * 256;                 // row = g&255, k16l = g>>8
    int row = g & 255, k16l = g >> 8;
    bf16x8 v = *(const bf16x8*)&tile[row][k16l * 8];
    *(bf16x8*)(dbase + ((size_t)(c * 8 + k16l) * 256 + row) * 8) = v;
  }
}

// ---- 2. exact f32 row sum-of-squares (codebook) -----------------------------
__global__ __launch_bounds__(256)
void rowsumsq(const float* __restrict__ src, float* __restrict__ dst, int nrows) {
  int gw = (blockIdx.x * 256 + threadIdx.x) >> 6;
  if (gw >= nrows) return;
  int lane = threadIdx.x & 63;
  const float4* s4 = (const float4*)(src + (size_t)gw * D);
  float s = 0.f;
#pragma unroll
  for (int i = 0; i < 2; ++i) {
    float4 v = s4[lane + i * 64];
    s += v.x * v.x + v.y * v.y + v.z * v.z + v.w * v.w;
  }
#pragma unroll
  for (int off = 32; off > 0; off >>= 1) s += __shfl_down(s, off, 64);
  if (lane == 0) dst[gw] = s;
}

// ---- 3. 256x256-tile BK=64 GEMM, decorrelated, 2-phase dbuf -----------------
// 512 threads = 8 waves (wr in {0,1} x wc in {0..3}). Wave tile: 128 rows x
// 64 codes. Swapped mfma(b, a): acc[nc][m][q] -> code = ct*256 + wc*64 +
// nc*16 + lh*4 + q, row = mt*256 + wr*128 + m*16 + lr.
__global__ __launch_bounds__(512, 1)
void vq_gemm256(const __hip_bfloat16* __restrict__ Apack,
                const __hip_bfloat16* __restrict__ Bpack,
                const float* __restrict__ e_sq,
                ulonglong2* __restrict__ cand2) {
  extern __shared__ __hip_bfloat16 smem[];
  // granule map (16 B each): buf*4096 + {A: 0..2047, B: 2048..4095}

  const int tid = threadIdx.x;
  const int w = tid >> 6, l = tid & 63;
  const int wr = w >> 2, wc = w & 3;
  const int lr = l & 15, lh = l >> 4;

  // Decorrelated diagonal map: concurrent blocks cover distinct ct; phase
  // rotation staggers the K-slab each block stages at any instant.
  const int bid = blockIdx.x;
  const int mt = bid & 63;                   // 64 m-tiles
  const int ct = ((bid >> 6) + mt) & 31;     // 32 c-tiles, diagonal
  const int phase = bid & 7;                 // K-phase rotation

  const __hip_bfloat16* Abase = Apack + (size_t)mt * TILEG;
  const __hip_bfloat16* Bbase = Bpack + (size_t)ct * TILEG;

  f32x4 acc[4][8] = {};

#define STAGE(buf, u)                                                           \
  do {                                                                          \
    _Pragma("unroll")                                                           \
    for (int i = 0; i < 4; ++i) {                                               \
      const int g = tid + i * 512;                                              \
      gload16(Abase + ((size_t)(u) * 2048 + g) * 8,                             \
              smem + ((size_t)(buf) * 4096 + g) * 8);                           \
      gload16(Bbase + ((size_t)(u) * 2048 + g) * 8,                             \
              smem + ((size_t)(buf) * 4096 + 2048 + g) * 8);                    \
    }                                                                           \
  } while (0)

#define COMPUTE(buf)                                                            \
  do {                                                                          \
    const bf16x8* Ag = (const bf16x8*)smem + (buf) * 4096;                      \
    const bf16x8* Bg = Ag + 2048;                                               \
    _Pragma("unroll")                                                           \
    for (int kk = 0; kk < 2; ++kk) {                                            \
      const int kb = (kk * 4 + lh) * 256;                                       \
      bf16x8 a[8], b[4];                                                        \
      _Pragma("unroll")                                                         \
      for (int nc = 0; nc < 4; ++nc) b[nc] = Bg[kb + wc * 64 + nc * 16 + lr];   \
      _Pragma("unroll")                                                         \
      for (int m = 0; m < 8; ++m)   a[m] = Ag[kb + wr * 128 + m * 16 + lr];     \
      _Pragma("unroll")                                                         \
      for (int nc = 0; nc < 4; ++nc)                                            \
        _Pragma("unroll")                                                       \
        for (int m = 0; m < 8; ++m)                                             \
          acc[nc][m] = __builtin_amdgcn_mfma_f32_16x16x32_bf16(b[nc], a[m],     \
                                                               acc[nc][m], 0, 0, 0); \
    }                                                                           \
  } while (0)

  STAGE(0, phase);
  __syncthreads();
#pragma unroll 1
  for (int t = 0; t < NSTEP - 1; ++t) {
    const int cur = t & 1;
    STAGE(cur ^ 1, (t + 1 + phase) & 7);   // prefetch next rotated slab
    COMPUTE(cur);
    __syncthreads();                       // one barrier per step
  }
  COMPUTE((NSTEP - 1) & 1);
#undef STAGE
#undef COMPUTE

  // ---- epilogue: per-row top-2 keys over this wave's 64-code strip ----
  const int col0 = ct * 256 + wc * 64;
  float es[4][4];
#pragma unroll
  for (int nc = 0; nc < 4; ++nc) {
    float4 e4 = *(const float4*)&e_sq[col0 + nc * 16 + lh * 4];
    es[nc][0] = e4.x; es[nc][1] = e4.y; es[nc][2] = e4.z; es[nc][3] = e4.w;
  }
#pragma unroll
  for (int m = 0; m < 8; ++m) {
    unsigned long long k1 = KMAX, k2 = KMAX;
#pragma unroll
    for (int nc = 0; nc < 4; ++nc)
#pragma unroll
      for (int q = 0; q < 4; ++q) {
        int code = col0 + nc * 16 + lh * 4 + q;
        kins2(score_key(es[nc][q] - 2.0f * acc[nc][m][q], code), k1, k2);
      }
#pragma unroll
    for (int s = 16; s <= 32; s <<= 1) {     // reduce over lh (4 lanes per lr)
      unsigned long long o1 = __shfl_xor(k1, s, 64);
      unsigned long long o2 = __shfl_xor(k2, s, 64);
      kins2(o1, k1, k2);
      kins2(o2, k1, k2);
    }
    if (lh == 0) {
      int gRow = mt * 256 + wr * 128 + m * 16 + lr;
      cand2[(size_t)gRow * 128 + ct * 4 + wc] = make_ulonglong2(k1, k2);
    }
  }
}

// ---- 4. global top-4 over 256 keys/row, exact f32 rescore, gather -----------
__global__ __launch_bounds__(256)
void vq_merge4(const float* __restrict__ x, const float* __restrict__ cb,
               const float* __restrict__ values, const float* __restrict__ e_sq,
               const ulonglong2* __restrict__ cand2, float* __restrict__ out) {
  int row = blockIdx.x * 4 + (threadIdx.x >> 6);
  int l = threadIdx.x & 63;

  unsigned long long k0 = KMAX, k1 = KMAX, k2 = KMAX, k3 = KMAX;
  const ulonglong2* base = cand2 + (size_t)row * 128;
#pragma unroll
  for (int u = 0; u < 2; ++u) {
    ulonglong2 e = base[l + 64 * u];
    kins4(e.x, k0, k1, k2, k3);
    kins4(e.y, k0, k1, k2, k3);
  }
#pragma unroll
  for (int s = 1; s < 64; s <<= 1) {
    unsigned long long o0 = __shfl_xor(k0, s, 64), o1 = __shfl_xor(k1, s, 64);
    unsigned long long o2 = __shfl_xor(k2, s, 64), o3 = __shfl_xor(k3, s, 64);
    kins4(o0, k0, k1, k2, k3); kins4(o1, k0, k1, k2, k3);
    kins4(o2, k0, k1, k2, k3); kins4(o3, k0, k1, k2, k3);
  }
  int i0 = (int)(k0 & 8191), i1 = (int)(k1 & 8191);
  int i2 = (int)(k2 & 8191), i3 = (int)(k3 & 8191);

  // exact f32 rescore (deterministic order)
  const float4* xr = (const float4*)(x + (size_t)row * D);
  const float4* c0 = (const float4*)(cb + (size_t)i0 * D);
  const float4* c1 = (const float4*)(cb + (size_t)i1 * D);
  const float4* c2 = (const float4*)(cb + (size_t)i2 * D);
  const float4* c3 = (const float4*)(cb + (size_t)i3 * D);
  float xsq = 0.f, t0 = 0.f, t1 = 0.f, t2 = 0.f, t3 = 0.f;
#pragma unroll
  for (int u = 0; u < 2; ++u) {
    float4 xv = xr[l + 64 * u];
    float4 a = c0[l + 64 * u], b = c1[l + 64 * u];
    float4 c = c2[l + 64 * u], e = c3[l + 64 * u];
    xsq += xv.x * xv.x + xv.y * xv.y + xv.z * xv.z + xv.w * xv.w;
    t0 += xv.x * a.x + xv.y * a.y + xv.z * a.z + xv.w * a.w;
    t1 += xv.x * b.x + xv.y * b.y + xv.z * b.z + xv.w * b.w;
    t2 += xv.x * c.x + xv.y * c.y + xv.z * c.z + xv.w * c.w;
    t3 += xv.x * e.x + xv.y * e.y + xv.z * e.z + xv.w * e.w;
  }
#pragma unroll
  for (int s = 1; s < 64; s <<= 1) {
    xsq += __shfl_xor(xsq, s, 64);
    t0 += __shfl_xor(t0, s, 64); t1 += __shfl_xor(t1, s, 64);
    t2 += __shfl_xor(t2, s, 64); t3 += __shfl_xor(t3, s, 64);
  }
  float D0 = xsq - 2.0f * t0 + e_sq[i0];
  float D1 = xsq - 2.0f * t1 + e_sq[i1];
  float D2 = xsq - 2.0f * t2 + e_sq[i2];
  float D3 = xsq - 2.0f * t3 + e_sq[i3];
  float bdist = D0; int best = i0;
  if (D1 < bdist || (D1 == bdist && i1 < best)) { bdist = D1; best = i1; }
  if (D2 < bdist || (D2 == bdist && i2 < best)) { bdist = D2; best = i2; }
  if (D3 < bdist || (D3 == bdist && i3 < best)) { bdist = D3; best = i3; }

  const float4* vsrc = (const float4*)(values + (size_t)best * D);
  float4* dst = (float4*)(out + (size_t)row * D);
  dst[l] = vsrc[l];
  dst[l + 64] = vsrc[l + 64];
}

// ============================================================================
extern "C" void kernel_launch(void* const* d_in, const int* in_sizes, int n_in,
                              void* d_out, int out_size, void* d_ws, size_t ws_size,
                              hipStream_t stream) {
  const float* x      = (const float*)d_in[0];
  const float* cb     = (const float*)d_in[1];
  const float* values = (const float*)d_in[2];
  float* out = (float*)d_out;

  const size_t A_BYTES = (size_t)M * KH * 2;          // 16 MB
  const size_t B_BYTES = (size_t)NCODE * KH * 2;      // 8 MB
  const size_t C_BYTES = (size_t)M * 128 * 16;        // 32 MB (key pairs)

  char* base = (char*)d_ws;
  __hip_bfloat16* Apack = (__hip_bfloat16*)base;
  __hip_bfloat16* Bpack = (__hip_bfloat16*)(base + A_BYTES);
  ulonglong2* cand2 = (ulonglong2*)(base + A_BYTES + B_BYTES);
  float* e_sq = (float*)(base + A_BYTES + B_BYTES + C_BYTES);

  const int LDS_GEMM = 131072;   // 2 x (32 KB A + 32 KB B)
  (void)hipFuncSetAttribute(reinterpret_cast<const void*>(vq_gemm256),
                            hipFuncAttributeMaxDynamicSharedMemorySize, LDS_GEMM);

  prep256<<<(M / 256) * 8, 256, 0, stream>>>(x, Apack);
  prep256<<<(NCODE / 256) * 8, 256, 0, stream>>>(cb, Bpack);
  rowsumsq<<<NCODE / 4, 256, 0, stream>>>(cb, e_sq, NCODE);
  vq_gemm256<<<(M / 256) * (NCODE / 256), 512, LDS_GEMM, stream>>>(
      Apack, Bpack, e_sq, cand2);
  vq_merge4<<<M / 4, 256, 0, stream>>>(x, cb, values, e_sq, cand2, out);
}

// Round 12
// 740.026 us; speedup vs baseline: 1.2443x; 1.0809x over previous
//
#include <hip/hip_runtime.h>
#include <hip/hip_bf16.h>

// VectorQuantize: argmin_k ||x - e_k||^2 then gather values[k].
// R12 = R7/R11 GEMM structure (256x256 tile, BK=64, 2-phase, one barrier per
// step -- 635 us measured) with INT8 operands: R1-R11 established that wall
// time tracks staged operand bytes at a ~2 TB/s device service rate
// (MSHR x latency bound), so halving bytes is the remaining lever.
// Per-row symmetric quantization (scale = maxabs/127); score =
// e_sq[k] - 2*sx[row]*se[k]*idot (i32 dot exact, < 2^24 so float-exact);
// per-wave top-2 sortable keys -> global top-4 -> exact f32 rescore
// (np tie semantics) -> gather values[best]. Any within-instruction
// k-permutation of the i8 fragments cancels between A and B packs.
//
// Pack layout (granule = 16 i8 = 16 B): P[tile256][k16 0..31][row 0..255][16].
// K-step t stages k16 = 4t..4t+3 (16 KB A + 16 KB B), granule index f
// identical in global and LDS -> gload_lds lane-linear.

#define D      512
#define M      16384
#define NCODE  8192
#define NSTEP  8           // K=512 / BK=64
#define TILEB  131072      // bytes per 256-row i8 tile (256*512)

typedef int  i32x4 __attribute__((ext_vector_type(4)));
typedef float f32x4 __attribute__((ext_vector_type(4)));

#define KMAX 0xFFFFFFFFFFFFFFFFull

__device__ __forceinline__ void gload16(const void* g, void* l) {
  __builtin_amdgcn_global_load_lds(
      (const __attribute__((address_space(1))) void*)g,
      (__attribute__((address_space(3))) void*)l, 16, 0, 0);
}

__device__ __forceinline__ unsigned long long score_key(float sc, int code) {
  unsigned int u = __float_as_uint(sc);
  unsigned int su = u ^ ((unsigned int)((int)u >> 31) | 0x80000000u);
  return ((unsigned long long)su << 32) | (unsigned int)code;
}

__device__ __forceinline__ void kins2(unsigned long long k,
                                      unsigned long long& k1, unsigned long long& k2) {
  if (k < k1) { k2 = k1; k1 = k; }
  else if (k < k2) { k2 = k; }
}

__device__ __forceinline__ void kins4(unsigned long long k,
    unsigned long long& k0, unsigned long long& k1,
    unsigned long long& k2, unsigned long long& k3) {
  if (k < k0)      { k3 = k2; k2 = k1; k1 = k0; k0 = k; }
  else if (k < k1) { k3 = k2; k2 = k1; k1 = k; }
  else if (k < k2) { k3 = k2; k2 = k; }
  else if (k < k3) { k3 = k; }
}

// ---- 1. per-row scales (+ e_sq for codebook) --------------------------------
// One wave per row over M + NCODE rows.
__global__ __launch_bounds__(256)
void scales_kernel(const float* __restrict__ x, const float* __restrict__ cb,
                   float* __restrict__ qmul_x, float* __restrict__ sval_x,
                   float* __restrict__ qmul_e, float* __restrict__ sval_e,
                   float* __restrict__ e_sq) {
  int gw = (blockIdx.x * 256 + threadIdx.x) >> 6;
  int lane = threadIdx.x & 63;
  bool isx = gw < M;
  int row = isx ? gw : gw - M;
  const float4* s4 = (const float4*)((isx ? x : cb) + (size_t)row * D);
  float ma = 0.f, ss = 0.f;
#pragma unroll
  for (int i = 0; i < 2; ++i) {
    float4 v = s4[lane + i * 64];
    ma = fmaxf(ma, fmaxf(fmaxf(fabsf(v.x), fabsf(v.y)), fmaxf(fabsf(v.z), fabsf(v.w))));
    ss += v.x * v.x + v.y * v.y + v.z * v.z + v.w * v.w;
  }
#pragma unroll
  for (int off = 32; off > 0; off >>= 1) {
    ma = fmaxf(ma, __shfl_down(ma, off, 64));
    ss += __shfl_down(ss, off, 64);
  }
  if (lane == 0) {
    ma = fmaxf(ma, 1e-30f);
    if (isx) { qmul_x[row] = 127.0f / ma; sval_x[row] = ma / 127.0f; }
    else     { qmul_e[row] = 127.0f / ma; sval_e[row] = ma / 127.0f; e_sq[row] = ss; }
  }
}

// ---- 2. f32 -> i8 256-row tile-transposed pack ------------------------------
// Grid: (nrows/256) * 8 chunks of 64 cols. Granule = 16 consecutive k of a row.
__global__ __launch_bounds__(256)
void prep_i8(const float* __restrict__ src, const float* __restrict__ qmul,
             char* __restrict__ dst) {
  __shared__ char tile[256][80];   // 20 KB, 16B-aligned rows
  const int tid = threadIdx.x;
  const int c = blockIdx.x & 7, t = blockIdx.x >> 3;
  const float* srow = src + (size_t)t * 256 * D;
  char* dbase = dst + (size_t)t * TILEB;

#pragma unroll
  for (int j = 0; j < 4; ++j) {
    int f = tid + j * 256;               // 1024 granules: row = f>>2, k16l = f&3
    int row = f >> 2, k16l = f & 3;
    const float4* p = (const float4*)(srow + (size_t)row * D + c * 64 + k16l * 16);
    float qm = qmul[t * 256 + row];
    union { i32x4 v; signed char b[16]; } pk;
#pragma unroll
    for (int u = 0; u < 4; ++u) {
      float4 v = p[u];
      float vv[4] = {v.x, v.y, v.z, v.w};
#pragma unroll
      for (int e = 0; e < 4; ++e) {
        int q = __float2int_rn(vv[e] * qm);
        q = q > 127 ? 127 : (q < -127 ? -127 : q);
        pk.b[u * 4 + e] = (signed char)q;
      }
    }
    *(i32x4*)&tile[row][k16l * 16] = pk.v;
  }
  __syncthreads();
#pragma unroll
  for (int j = 0; j < 4; ++j) {
    int g = tid + j * 256;               // out granule: row = g&255, k16l = g>>8
    int row = g & 255, k16l = g >> 8;
    i32x4 v = *(const i32x4*)&tile[row][k16l * 16];
    *(i32x4*)(dbase + (((size_t)(c * 4 + k16l) * 256 + row) * 16)) = v;
  }
}

// ---- 3. 256x256-tile BK=64 int8 GEMM, 2-phase dbuf, per-wave top-2 ----------
// 512 threads = 8 waves (wr in {0,1} x wc in {0..3}). Wave tile: 128 rows x
// 64 codes. Swapped mfma_i32_16x16x64_i8(b, a): acc[nc][m][q] -> code =
// ct*256 + wc*64 + nc*16 + lh*4 + q, row = mt*256 + wr*128 + m*16 + lr.
__global__ __launch_bounds__(512, 1)
void vq_gemm_i8(const char* __restrict__ Apack, const char* __restrict__ Bpack,
                const float* __restrict__ e_sq,
                const float* __restrict__ sval_x, const float* __restrict__ sval_e,
                ulonglong2* __restrict__ cand2) {
  extern __shared__ char smem[];
  // granule map (16 B): buf*2048 + {A: 0..1023, B: 1024..2047}; 2 bufs = 64 KB

  const int tid = threadIdx.x;
  const int w = tid >> 6, l = tid & 63;
  const int wr = w >> 2, wc = w & 3;
  const int lr = l & 15, lh = l >> 4;

  // R7's XCD-pinned L2-aware map (R11 proved correlation is perf-neutral).
  const int bid = blockIdx.x;
  const int xcd = bid & 7, idx = bid >> 3;   // 256 blocks per XCD
  const int mt = xcd * 8 + (idx & 7);        // 64 m-tiles
  const int ct = idx >> 3;                   // 32 c-tiles

  const char* Abase = Apack + (size_t)mt * TILEB;
  const char* Bbase = Bpack + (size_t)ct * TILEB;

  i32x4 acc[4][8] = {};

#define STAGE(buf, t)                                                          \
  do {                                                                         \
    _Pragma("unroll")                                                          \
    for (int i = 0; i < 2; ++i) {                                              \
      const int g = tid + i * 512;                                             \
      gload16(Abase + ((size_t)(t) * 1024 + g) * 16,                           \
              smem + ((size_t)(buf) * 2048 + g) * 16);                         \
      gload16(Bbase + ((size_t)(t) * 1024 + g) * 16,                           \
              smem + ((size_t)(buf) * 2048 + 1024 + g) * 16);                  \
    }                                                                          \
  } while (0)

#define COMPUTE(buf)                                                           \
  do {                                                                         \
    const i32x4* Ag = (const i32x4*)smem + (buf) * 2048;                       \
    const i32x4* Bg = Ag + 1024;                                               \
    i32x4 a[8], b[4];                                                          \
    _Pragma("unroll")                                                          \
    for (int nc = 0; nc < 4; ++nc) b[nc] = Bg[lh * 256 + wc * 64 + nc * 16 + lr]; \
    _Pragma("unroll")                                                          \
    for (int m = 0; m < 8; ++m)   a[m] = Ag[lh * 256 + wr * 128 + m * 16 + lr];   \
    _Pragma("unroll")                                                          \
    for (int nc = 0; nc < 4; ++nc)                                             \
      _Pragma("unroll")                                                        \
      for (int m = 0; m < 8; ++m)                                              \
        acc[nc][m] = __builtin_amdgcn_mfma_i32_16x16x64_i8(b[nc], a[m],        \
                                                           acc[nc][m], 0, 0, 0); \
  } while (0)

  STAGE(0, 0);
  __syncthreads();
#pragma unroll 1
  for (int t = 0; t < NSTEP - 1; ++t) {
    const int cur = t & 1;
    STAGE(cur ^ 1, t + 1);       // prefetch issued before compute
    COMPUTE(cur);
    __syncthreads();             // one barrier per step
  }
  COMPUTE((NSTEP - 1) & 1);
#undef STAGE
#undef COMPUTE

  // ---- epilogue: per-row top-2 keys over this wave's 64-code strip ----
  const int col0 = ct * 256 + wc * 64;
  float es[4][4], sev[4][4], sxv[8];
#pragma unroll
  for (int nc = 0; nc < 4; ++nc) {
    float4 e4 = *(const float4*)&e_sq[col0 + nc * 16 + lh * 4];
    float4 s4 = *(const float4*)&sval_e[col0 + nc * 16 + lh * 4];
    es[nc][0] = e4.x; es[nc][1] = e4.y; es[nc][2] = e4.z; es[nc][3] = e4.w;
    sev[nc][0] = s4.x; sev[nc][1] = s4.y; sev[nc][2] = s4.z; sev[nc][3] = s4.w;
  }
#pragma unroll
  for (int m = 0; m < 8; ++m)
    sxv[m] = sval_x[mt * 256 + wr * 128 + m * 16 + lr];

#pragma unroll
  for (int m = 0; m < 8; ++m) {
    unsigned long long k1 = KMAX, k2 = KMAX;
    const float sx2 = 2.0f * sxv[m];
#pragma unroll
    for (int nc = 0; nc < 4; ++nc)
#pragma unroll
      for (int q = 0; q < 4; ++q) {
        int code = col0 + nc * 16 + lh * 4 + q;
        float sc = es[nc][q] - sx2 * sev[nc][q] * (float)acc[nc][m][q];
        kins2(score_key(sc, code), k1, k2);
      }
#pragma unroll
    for (int s = 16; s <= 32; s <<= 1) {     // reduce over lh (4 lanes per lr)
      unsigned long long o1 = __shfl_xor(k1, s, 64);
      unsigned long long o2 = __shfl_xor(k2, s, 64);
      kins2(o1, k1, k2);
      kins2(o2, k1, k2);
    }
    if (lh == 0) {
      int gRow = mt * 256 + wr * 128 + m * 16 + lr;
      cand2[(size_t)gRow * 128 + ct * 4 + wc] = make_ulonglong2(k1, k2);
    }
  }
}

// ---- 4. global top-4 over 256 keys/row, exact f32 rescore, gather -----------
__global__ __launch_bounds__(256)
void vq_merge4(const float* __restrict__ x, const float* __restrict__ cb,
               const float* __restrict__ values, const float* __restrict__ e_sq,
               const ulonglong2* __restrict__ cand2, float* __restrict__ out) {
  int row = blockIdx.x * 4 + (threadIdx.x >> 6);
  int l = threadIdx.x & 63;

  unsigned long long k0 = KMAX, k1 = KMAX, k2 = KMAX, k3 = KMAX;
  const ulonglong2* base = cand2 + (size_t)row * 128;
#pragma unroll
  for (int u = 0; u < 2; ++u) {
    ulonglong2 e = base[l + 64 * u];
    kins4(e.x, k0, k1, k2, k3);
    kins4(e.y, k0, k1, k2, k3);
  }
#pragma unroll
  for (int s = 1; s < 64; s <<= 1) {
    unsigned long long o0 = __shfl_xor(k0, s, 64), o1 = __shfl_xor(k1, s, 64);
    unsigned long long o2 = __shfl_xor(k2, s, 64), o3 = __shfl_xor(k3, s, 64);
    kins4(o0, k0, k1, k2, k3); kins4(o1, k0, k1, k2, k3);
    kins4(o2, k0, k1, k2, k3); kins4(o3, k0, k1, k2, k3);
  }
  int i0 = (int)(k0 & 8191), i1 = (int)(k1 & 8191);
  int i2 = (int)(k2 & 8191), i3 = (int)(k3 & 8191);

  // exact f32 rescore (deterministic order)
  const float4* xr = (const float4*)(x + (size_t)row * D);
  const float4* c0 = (const float4*)(cb + (size_t)i0 * D);
  const float4* c1 = (const float4*)(cb + (size_t)i1 * D);
  const float4* c2 = (const float4*)(cb + (size_t)i2 * D);
  const float4* c3 = (const float4*)(cb + (size_t)i3 * D);
  float xsq = 0.f, t0 = 0.f, t1 = 0.f, t2 = 0.f, t3 = 0.f;
#pragma unroll
  for (int u = 0; u < 2; ++u) {
    float4 xv = xr[l + 64 * u];
    float4 a = c0[l + 64 * u], b = c1[l + 64 * u];
    float4 c = c2[l + 64 * u], e = c3[l + 64 * u];
    xsq += xv.x * xv.x + xv.y * xv.y + xv.z * xv.z + xv.w * xv.w;
    t0 += xv.x * a.x + xv.y * a.y + xv.z * a.z + xv.w * a.w;
    t1 += xv.x * b.x + xv.y * b.y + xv.z * b.z + xv.w * b.w;
    t2 += xv.x * c.x + xv.y * c.y + xv.z * c.z + xv.w * c.w;
    t3 += xv.x * e.x + xv.y * e.y + xv.z * e.z + xv.w * e.w;
  }
#pragma unroll
  for (int s = 1; s < 64; s <<= 1) {
    xsq += __shfl_xor(xsq, s, 64);
    t0 += __shfl_xor(t0, s, 64); t1 += __shfl_xor(t1, s, 64);
    t2 += __shfl_xor(t2, s, 64); t3 += __shfl_xor(t3, s, 64);
  }
  float D0 = xsq - 2.0f * t0 + e_sq[i0];
  float D1 = xsq - 2.0f * t1 + e_sq[i1];
  float D2 = xsq - 2.0f * t2 + e_sq[i2];
  float D3 = xsq - 2.0f * t3 + e_sq[i3];
  float bdist = D0; int best = i0;
  if (D1 < bdist || (D1 == bdist && i1 < best)) { bdist = D1; best = i1; }
  if (D2 < bdist || (D2 == bdist && i2 < best)) { bdist = D2; best = i2; }
  if (D3 < bdist || (D3 == bdist && i3 < best)) { bdist = D3; best = i3; }

  const float4* vsrc = (const float4*)(values + (size_t)best * D);
  float4* dst = (float4*)(out + (size_t)row * D);
  dst[l] = vsrc[l];
  dst[l + 64] = vsrc[l + 64];
}

// ============================================================================
extern "C" void kernel_launch(void* const* d_in, const int* in_sizes, int n_in,
                              void* d_out, int out_size, void* d_ws, size_t ws_size,
                              hipStream_t stream) {
  const float* x      = (const float*)d_in[0];
  const float* cb     = (const float*)d_in[1];
  const float* values = (const float*)d_in[2];
  float* out = (float*)d_out;

  const size_t A_BYTES = (size_t)M * D;               // 8 MB (i8)
  const size_t B_BYTES = (size_t)NCODE * D;           // 4 MB (i8)
  const size_t C_BYTES = (size_t)M * 128 * 16;        // 32 MB (key pairs)

  char* base = (char*)d_ws;
  char* Apack = base;
  char* Bpack = base + A_BYTES;
  ulonglong2* cand2 = (ulonglong2*)(base + A_BYTES + B_BYTES);
  float* qmul_x = (float*)(base + A_BYTES + B_BYTES + C_BYTES);
  float* sval_x = qmul_x + M;
  float* qmul_e = sval_x + M;
  float* sval_e = qmul_e + NCODE;
  float* e_sq   = sval_e + NCODE;

  const int LDS_GEMM = 65536;   // 2 x (16 KB A + 16 KB B)
  (void)hipFuncSetAttribute(reinterpret_cast<const void*>(vq_gemm_i8),
                            hipFuncAttributeMaxDynamicSharedMemorySize, LDS_GEMM);

  scales_kernel<<<(M + NCODE) / 4, 256, 0, stream>>>(
      x, cb, qmul_x, sval_x, qmul_e, sval_e, e_sq);
  prep_i8<<<(M / 256) * 8, 256, 0, stream>>>(x, qmul_x, Apack);
  prep_i8<<<(NCODE / 256) * 8, 256, 0, stream>>>(cb, qmul_e, Bpack);
  vq_gemm_i8<<<(M / 256) * (NCODE / 256), 512, LDS_GEMM, stream>>>(
      Apack, Bpack, e_sq, sval_x, sval_e, cand2);
  vq_merge4<<<M / 4, 256, 0, stream>>>(x, cb, values, e_sq, cand2, out);
}

// Round 13
// 736.098 us; speedup vs baseline: 1.2510x; 1.0053x over previous
//
#include <hip/hip_runtime.h>
#include <hip/hip_bf16.h>

// VectorQuantize: argmin_k ||x - e_k||^2 then gather values[k].
// R13: int8 GEMM in R5's HIGH-OCCUPANCY geometry. R1-R12 ledger fits one law:
// staging service ~0.4-0.55 B/cyc per WAVE (latency-bound chains), aggregate
// rate tracks resident waves/CU (R5's 16 waves/CU = 6.6 B/cyc/CU was the best;
// all 8-wave rounds sat at 2.2-3.9). So: 128x128 tile, 4-wave blocks (wave
// tile 64x64), BK=64 (one mfma_i32_16x16x64_i8 per frag pair), 32 KB LDS
// dbuf -> ~4 blocks/CU = ~16 waves/CU at unchanged 1.05 GB sweep traffic.
// Same quantization/rescue as R12: per-row symmetric i8, score =
// e_sq - 2*sx*se*idot, per-wave top-2 sortable keys -> global top-4 ->
// exact f32 rescore (np tie semantics) -> gather values[best].
//
// Pack layout (granule = 16 i8 = 16 B): P[tile128][k16 0..31][row 0..127][16].
// K-step t (BK=64) stages k16 = 4t..4t+3: 512-granule slab (8 KB), granule
// index f identical in global and LDS -> gload_lds lane-linear.

#define D      512
#define M      16384
#define NCODE  8192
#define NSTEP  8           // K=512 / BK=64
#define TILEB  65536       // bytes per 128-row i8 tile (128*512)

typedef int   i32x4 __attribute__((ext_vector_type(4)));
typedef float f32x4 __attribute__((ext_vector_type(4)));

#define KMAX 0xFFFFFFFFFFFFFFFFull

__device__ __forceinline__ void gload16(const void* g, void* l) {
  __builtin_amdgcn_global_load_lds(
      (const __attribute__((address_space(1))) void*)g,
      (__attribute__((address_space(3))) void*)l, 16, 0, 0);
}

__device__ __forceinline__ unsigned long long score_key(float sc, int code) {
  unsigned int u = __float_as_uint(sc);
  unsigned int su = u ^ ((unsigned int)((int)u >> 31) | 0x80000000u);
  return ((unsigned long long)su << 32) | (unsigned int)code;
}

__device__ __forceinline__ void kins2(unsigned long long k,
                                      unsigned long long& k1, unsigned long long& k2) {
  if (k < k1) { k2 = k1; k1 = k; }
  else if (k < k2) { k2 = k; }
}

__device__ __forceinline__ void kins4(unsigned long long k,
    unsigned long long& k0, unsigned long long& k1,
    unsigned long long& k2, unsigned long long& k3) {
  if (k < k0)      { k3 = k2; k2 = k1; k1 = k0; k0 = k; }
  else if (k < k1) { k3 = k2; k2 = k1; k1 = k; }
  else if (k < k2) { k3 = k2; k2 = k; }
  else if (k < k3) { k3 = k; }
}

// ---- 1. per-row scales (+ e_sq for codebook) --------------------------------
__global__ __launch_bounds__(256)
void scales_kernel(const float* __restrict__ x, const float* __restrict__ cb,
                   float* __restrict__ qmul_x, float* __restrict__ sval_x,
                   float* __restrict__ qmul_e, float* __restrict__ sval_e,
                   float* __restrict__ e_sq) {
  int gw = (blockIdx.x * 256 + threadIdx.x) >> 6;
  int lane = threadIdx.x & 63;
  bool isx = gw < M;
  int row = isx ? gw : gw - M;
  const float4* s4 = (const float4*)((isx ? x : cb) + (size_t)row * D);
  float ma = 0.f, ss = 0.f;
#pragma unroll
  for (int i = 0; i < 2; ++i) {
    float4 v = s4[lane + i * 64];
    ma = fmaxf(ma, fmaxf(fmaxf(fabsf(v.x), fabsf(v.y)), fmaxf(fabsf(v.z), fabsf(v.w))));
    ss += v.x * v.x + v.y * v.y + v.z * v.z + v.w * v.w;
  }
#pragma unroll
  for (int off = 32; off > 0; off >>= 1) {
    ma = fmaxf(ma, __shfl_down(ma, off, 64));
    ss += __shfl_down(ss, off, 64);
  }
  if (lane == 0) {
    ma = fmaxf(ma, 1e-30f);
    if (isx) { qmul_x[row] = 127.0f / ma; sval_x[row] = ma / 127.0f; }
    else     { qmul_e[row] = 127.0f / ma; sval_e[row] = ma / 127.0f; e_sq[row] = ss; }
  }
}

// ---- 2. f32 -> i8 128-row tile-transposed pack ------------------------------
// Grid: (nrows/128) * 4 chunks of 128 cols (8 k16 each). Block 256.
__global__ __launch_bounds__(256)
void prep_i8t(const float* __restrict__ src, const float* __restrict__ qmul,
              char* __restrict__ dst) {
  __shared__ char tile[128][144];   // 18 KB, 16B-aligned rows
  const int tid = threadIdx.x;
  const int c = blockIdx.x & 3, t = blockIdx.x >> 2;
  const float* srow = src + (size_t)t * 128 * D;
  char* dbase = dst + (size_t)t * TILEB;

#pragma unroll
  for (int j = 0; j < 4; ++j) {
    int f = tid + j * 256;               // 1024 granules: row = f>>3, k16l = f&7
    int row = f >> 3, k16l = f & 7;
    const float4* p = (const float4*)(srow + (size_t)row * D + c * 128 + k16l * 16);
    float qm = qmul[t * 128 + row];
    union { i32x4 v; signed char b[16]; } pk;
#pragma unroll
    for (int u = 0; u < 4; ++u) {
      float4 v = p[u];
      float vv[4] = {v.x, v.y, v.z, v.w};
#pragma unroll
      for (int e = 0; e < 4; ++e) {
        int q = __float2int_rn(vv[e] * qm);
        q = q > 127 ? 127 : (q < -127 ? -127 : q);
        pk.b[u * 4 + e] = (signed char)q;
      }
    }
    *(i32x4*)&tile[row][k16l * 16] = pk.v;
  }
  __syncthreads();
#pragma unroll
  for (int j = 0; j < 4; ++j) {
    int g = tid + j * 256;               // out granule: row = g&127, k16l = g>>7
    int row = g & 127, k16l = g >> 7;
    i32x4 v = *(const i32x4*)&tile[row][k16l * 16];
    *(i32x4*)(dbase + (((size_t)(c * 8 + k16l) * 128 + row) * 16)) = v;
  }
}

// ---- 3. 128x128-tile BK=64 i8 GEMM, 4-wave blocks, ~16 waves/CU -------------
// 256 threads = 4 waves (wr, wc in {0,1}). Wave tile: 64 rows x 64 codes.
// Swapped mfma_i32_16x16x64_i8(b, a): acc[nc][m][q] -> code = ct*128 + wc*64 +
// nc*16 + lh*4 + q, row = mt*128 + wr*64 + m*16 + lr.
__global__ __launch_bounds__(256, 4)
void vq_gemm_i8s(const char* __restrict__ Apack, const char* __restrict__ Bpack,
                 const float* __restrict__ e_sq,
                 const float* __restrict__ sval_x, const float* __restrict__ sval_e,
                 ulonglong2* __restrict__ cand2) {
  __shared__ char As[2][512 * 16];   // 2 x 8 KB
  __shared__ char Bs[2][512 * 16];   // 2 x 8 KB

  const int tid = threadIdx.x;
  const int w = tid >> 6, l = tid & 63;
  const int wr = w >> 1, wc = w & 1;
  const int lr = l & 15, lh = l >> 4;

  // XCD-pinned L2-aware map (R11: ordering is perf-neutral; keep L2-friendly).
  const int bid = blockIdx.x;
  const int xcd = bid & 7, idx = bid >> 3;   // 1024 blocks per XCD
  const int mt = xcd * 16 + (idx & 15);      // 128 m-tiles
  const int ct = idx >> 4;                   // 64 c-tiles

  const char* Abase = Apack + (size_t)mt * TILEB;
  const char* Bbase = Bpack + (size_t)ct * TILEB;

  i32x4 acc[4][4] = {};

#define STAGE(buf, t)                                                          \
  do {                                                                         \
    _Pragma("unroll")                                                          \
    for (int i = 0; i < 2; ++i) {                                              \
      const int g = tid + i * 256;                                             \
      gload16(Abase + ((size_t)(t) * 512 + g) * 16, As[(buf)] + (size_t)g * 16); \
      gload16(Bbase + ((size_t)(t) * 512 + g) * 16, Bs[(buf)] + (size_t)g * 16); \
    }                                                                          \
  } while (0)

#define COMPUTE(buf)                                                           \
  do {                                                                         \
    const i32x4* Ag = (const i32x4*)As[(buf)];                                 \
    const i32x4* Bg = (const i32x4*)Bs[(buf)];                                 \
    i32x4 a[4], b[4];                                                          \
    _Pragma("unroll")                                                          \
    for (int nc = 0; nc < 4; ++nc) b[nc] = Bg[lh * 128 + wc * 64 + nc * 16 + lr]; \
    _Pragma("unroll")                                                          \
    for (int m = 0; m < 4; ++m)   a[m] = Ag[lh * 128 + wr * 64 + m * 16 + lr];    \
    _Pragma("unroll")                                                          \
    for (int nc = 0; nc < 4; ++nc)                                             \
      _Pragma("unroll")                                                        \
      for (int m = 0; m < 4; ++m)                                              \
        acc[nc][m] = __builtin_amdgcn_mfma_i32_16x16x64_i8(b[nc], a[m],        \
                                                           acc[nc][m], 0, 0, 0); \
  } while (0)

  STAGE(0, 0);
  __syncthreads();
#pragma unroll 1
  for (int t = 0; t < NSTEP - 1; ++t) {
    const int cur = t & 1;
    STAGE(cur ^ 1, t + 1);       // prefetch issued before compute
    COMPUTE(cur);
    __syncthreads();             // one barrier per step
  }
  COMPUTE((NSTEP - 1) & 1);
#undef STAGE
#undef COMPUTE

  // ---- epilogue: per-row top-2 keys over this wave's 64-code strip ----
  const int col0 = ct * 128 + wc * 64;
  float es[4][4], sev[4][4], sxv[4];
#pragma unroll
  for (int nc = 0; nc < 4; ++nc) {
    float4 e4 = *(const float4*)&e_sq[col0 + nc * 16 + lh * 4];
    float4 s4 = *(const float4*)&sval_e[col0 + nc * 16 + lh * 4];
    es[nc][0] = e4.x; es[nc][1] = e4.y; es[nc][2] = e4.z; es[nc][3] = e4.w;
    sev[nc][0] = s4.x; sev[nc][1] = s4.y; sev[nc][2] = s4.z; sev[nc][3] = s4.w;
  }
#pragma unroll
  for (int m = 0; m < 4; ++m)
    sxv[m] = sval_x[mt * 128 + wr * 64 + m * 16 + lr];

#pragma unroll
  for (int m = 0; m < 4; ++m) {
    unsigned long long k1 = KMAX, k2 = KMAX;
    const float sx2 = 2.0f * sxv[m];
#pragma unroll
    for (int nc = 0; nc < 4; ++nc)
#pragma unroll
      for (int q = 0; q < 4; ++q) {
        int code = col0 + nc * 16 + lh * 4 + q;
        float sc = es[nc][q] - sx2 * sev[nc][q] * (float)acc[nc][m][q];
        kins2(score_key(sc, code), k1, k2);
      }
#pragma unroll
    for (int s = 16; s <= 32; s <<= 1) {     // reduce over lh (4 lanes per lr)
      unsigned long long o1 = __shfl_xor(k1, s, 64);
      unsigned long long o2 = __shfl_xor(k2, s, 64);
      kins2(o1, k1, k2);
      kins2(o2, k1, k2);
    }
    if (lh == 0) {
      int gRow = mt * 128 + wr * 64 + m * 16 + lr;
      cand2[(size_t)gRow * 128 + ct * 2 + wc] = make_ulonglong2(k1, k2);
    }
  }
}

// ---- 4. global top-4 over 256 keys/row, exact f32 rescore, gather -----------
__global__ __launch_bounds__(256)
void vq_merge4(const float* __restrict__ x, const float* __restrict__ cb,
               const float* __restrict__ values, const float* __restrict__ e_sq,
               const ulonglong2* __restrict__ cand2, float* __restrict__ out) {
  int row = blockIdx.x * 4 + (threadIdx.x >> 6);
  int l = threadIdx.x & 63;

  unsigned long long k0 = KMAX, k1 = KMAX, k2 = KMAX, k3 = KMAX;
  const ulonglong2* base = cand2 + (size_t)row * 128;
#pragma unroll
  for (int u = 0; u < 2; ++u) {
    ulonglong2 e = base[l + 64 * u];
    kins4(e.x, k0, k1, k2, k3);
    kins4(e.y, k0, k1, k2, k3);
  }
#pragma unroll
  for (int s = 1; s < 64; s <<= 1) {
    unsigned long long o0 = __shfl_xor(k0, s, 64), o1 = __shfl_xor(k1, s, 64);
    unsigned long long o2 = __shfl_xor(k2, s, 64), o3 = __shfl_xor(k3, s, 64);
    kins4(o0, k0, k1, k2, k3); kins4(o1, k0, k1, k2, k3);
    kins4(o2, k0, k1, k2, k3); kins4(o3, k0, k1, k2, k3);
  }
  int i0 = (int)(k0 & 8191), i1 = (int)(k1 & 8191);
  int i2 = (int)(k2 & 8191), i3 = (int)(k3 & 8191);

  // exact f32 rescore (deterministic order)
  const float4* xr = (const float4*)(x + (size_t)row * D);
  const float4* c0 = (const float4*)(cb + (size_t)i0 * D);
  const float4* c1 = (const float4*)(cb + (size_t)i1 * D);
  const float4* c2 = (const float4*)(cb + (size_t)i2 * D);
  const float4* c3 = (const float4*)(cb + (size_t)i3 * D);
  float xsq = 0.f, t0 = 0.f, t1 = 0.f, t2 = 0.f, t3 = 0.f;
#pragma unroll
  for (int u = 0; u < 2; ++u) {
    float4 xv = xr[l + 64 * u];
    float4 a = c0[l + 64 * u], b = c1[l + 64 * u];
    float4 c = c2[l + 64 * u], e = c3[l + 64 * u];
    xsq += xv.x * xv.x + xv.y * xv.y + xv.z * xv.z + xv.w * xv.w;
    t0 += xv.x * a.x + xv.y * a.y + xv.z * a.z + xv.w * a.w;
    t1 += xv.x * b.x + xv.y * b.y + xv.z * b.z + xv.w * b.w;
    t2 += xv.x * c.x + xv.y * c.y + xv.z * c.z + xv.w * c.w;
    t3 += xv.x * e.x + xv.y * e.y + xv.z * e.z + xv.w * e.w;
  }
#pragma unroll
  for (int s = 1; s < 64; s <<= 1) {
    xsq += __shfl_xor(xsq, s, 64);
    t0 += __shfl_xor(t0, s, 64); t1 += __shfl_xor(t1, s, 64);
    t2 += __shfl_xor(t2, s, 64); t3 += __shfl_xor(t3, s, 64);
  }
  float D0 = xsq - 2.0f * t0 + e_sq[i0];
  float D1 = xsq - 2.0f * t1 + e_sq[i1];
  float D2 = xsq - 2.0f * t2 + e_sq[i2];
  float D3 = xsq - 2.0f * t3 + e_sq[i3];
  float bdist = D0; int best = i0;
  if (D1 < bdist || (D1 == bdist && i1 < best)) { bdist = D1; best = i1; }
  if (D2 < bdist || (D2 == bdist && i2 < best)) { bdist = D2; best = i2; }
  if (D3 < bdist || (D3 == bdist && i3 < best)) { bdist = D3; best = i3; }

  const float4* vsrc = (const float4*)(values + (size_t)best * D);
  float4* dst = (float4*)(out + (size_t)row * D);
  dst[l] = vsrc[l];
  dst[l + 64] = vsrc[l + 64];
}

// ============================================================================
extern "C" void kernel_launch(void* const* d_in, const int* in_sizes, int n_in,
                              void* d_out, int out_size, void* d_ws, size_t ws_size,
                              hipStream_t stream) {
  const float* x      = (const float*)d_in[0];
  const float* cb     = (const float*)d_in[1];
  const float* values = (const float*)d_in[2];
  float* out = (float*)d_out;

  const size_t A_BYTES = (size_t)M * D;               // 8 MB (i8)
  const size_t B_BYTES = (size_t)NCODE * D;           // 4 MB (i8)
  const size_t C_BYTES = (size_t)M * 128 * 16;        // 32 MB (key pairs)

  char* base = (char*)d_ws;
  char* Apack = base;
  char* Bpack = base + A_BYTES;
  ulonglong2* cand2 = (ulonglong2*)(base + A_BYTES + B_BYTES);
  float* qmul_x = (float*)(base + A_BYTES + B_BYTES + C_BYTES);
  float* sval_x = qmul_x + M;
  float* qmul_e = sval_x + M;
  float* sval_e = qmul_e + NCODE;
  float* e_sq   = sval_e + NCODE;

  scales_kernel<<<(M + NCODE) / 4, 256, 0, stream>>>(
      x, cb, qmul_x, sval_x, qmul_e, sval_e, e_sq);
  prep_i8t<<<(M / 128) * 4, 256, 0, stream>>>(x, qmul_x, Apack);
  prep_i8t<<<(NCODE / 128) * 4, 256, 0, stream>>>(cb, qmul_e, Bpack);
  vq_gemm_i8s<<<(M / 128) * (NCODE / 128), 256, 0, stream>>>(
      Apack, Bpack, e_sq, sval_x, sval_e, cand2);
  vq_merge4<<<M / 4, 256, 0, stream>>>(x, cb, values, e_sq, cand2, out);
}

// Round 14
// 726.676 us; speedup vs baseline: 1.2672x; 1.0130x over previous
//
#include <hip/hip_runtime.h>
#include <hip/hip_bf16.h>

// VectorQuantize: argmin_k ||x - e_k||^2 then gather values[k].
// R14 = R13 (i8 128x128 BK=64 2-phase, 4-wave blocks, ~16 waves/CU, 571 us)
// with ONE change: CO-RESIDENCY block map. Dispatch places bids b, b+1024,
// b+2048... on ~the same CU (8192 blocks = 8 rounds of 1024), so
//   mt = (bid%1024)>>3,  ct = ((bid%1024)&7) + 8*(bid>>10)
// makes all concurrent+sequential blocks of a CU share ONE A-tile (64 KB i8)
// -> A-slab gload_lds goes L1/L2-hot after the first toucher. R1-R13 ledger:
// staging is latency-bound at ~0.4 B/cyc/wave; halving effective A latency
// is the remaining lever that doesn't trade waves for bytes.
// Quantization/rescue unchanged: per-row symmetric i8, score =
// e_sq - 2*sx*se*idot, per-wave top-2 sortable keys -> global top-4 ->
// exact f32 rescore (np tie semantics) -> gather values[best].

#define D      512
#define M      16384
#define NCODE  8192
#define NSTEP  8           // K=512 / BK=64
#define TILEB  65536       // bytes per 128-row i8 tile (128*512)

typedef int   i32x4 __attribute__((ext_vector_type(4)));
typedef float f32x4 __attribute__((ext_vector_type(4)));

#define KMAX 0xFFFFFFFFFFFFFFFFull

__device__ __forceinline__ void gload16(const void* g, void* l) {
  __builtin_amdgcn_global_load_lds(
      (const __attribute__((address_space(1))) void*)g,
      (__attribute__((address_space(3))) void*)l, 16, 0, 0);
}

__device__ __forceinline__ unsigned long long score_key(float sc, int code) {
  unsigned int u = __float_as_uint(sc);
  unsigned int su = u ^ ((unsigned int)((int)u >> 31) | 0x80000000u);
  return ((unsigned long long)su << 32) | (unsigned int)code;
}

__device__ __forceinline__ void kins2(unsigned long long k,
                                      unsigned long long& k1, unsigned long long& k2) {
  if (k < k1) { k2 = k1; k1 = k; }
  else if (k < k2) { k2 = k; }
}

__device__ __forceinline__ void kins4(unsigned long long k,
    unsigned long long& k0, unsigned long long& k1,
    unsigned long long& k2, unsigned long long& k3) {
  if (k < k0)      { k3 = k2; k2 = k1; k1 = k0; k0 = k; }
  else if (k < k1) { k3 = k2; k2 = k1; k1 = k; }
  else if (k < k2) { k3 = k2; k2 = k; }
  else if (k < k3) { k3 = k; }
}

// ---- 1. per-row scales (+ e_sq for codebook) --------------------------------
__global__ __launch_bounds__(256)
void scales_kernel(const float* __restrict__ x, const float* __restrict__ cb,
                   float* __restrict__ qmul_x, float* __restrict__ sval_x,
                   float* __restrict__ qmul_e, float* __restrict__ sval_e,
                   float* __restrict__ e_sq) {
  int gw = (blockIdx.x * 256 + threadIdx.x) >> 6;
  int lane = threadIdx.x & 63;
  bool isx = gw < M;
  int row = isx ? gw : gw - M;
  const float4* s4 = (const float4*)((isx ? x : cb) + (size_t)row * D);
  float ma = 0.f, ss = 0.f;
#pragma unroll
  for (int i = 0; i < 2; ++i) {
    float4 v = s4[lane + i * 64];
    ma = fmaxf(ma, fmaxf(fmaxf(fabsf(v.x), fabsf(v.y)), fmaxf(fabsf(v.z), fabsf(v.w))));
    ss += v.x * v.x + v.y * v.y + v.z * v.z + v.w * v.w;
  }
#pragma unroll
  for (int off = 32; off > 0; off >>= 1) {
    ma = fmaxf(ma, __shfl_down(ma, off, 64));
    ss += __shfl_down(ss, off, 64);
  }
  if (lane == 0) {
    ma = fmaxf(ma, 1e-30f);
    if (isx) { qmul_x[row] = 127.0f / ma; sval_x[row] = ma / 127.0f; }
    else     { qmul_e[row] = 127.0f / ma; sval_e[row] = ma / 127.0f; e_sq[row] = ss; }
  }
}

// ---- 2. f32 -> i8 128-row tile-transposed pack ------------------------------
__global__ __launch_bounds__(256)
void prep_i8t(const float* __restrict__ src, const float* __restrict__ qmul,
              char* __restrict__ dst) {
  __shared__ char tile[128][144];   // 18 KB, 16B-aligned rows
  const int tid = threadIdx.x;
  const int c = blockIdx.x & 3, t = blockIdx.x >> 2;
  const float* srow = src + (size_t)t * 128 * D;
  char* dbase = dst + (size_t)t * TILEB;

#pragma unroll
  for (int j = 0; j < 4; ++j) {
    int f = tid + j * 256;               // 1024 granules: row = f>>3, k16l = f&7
    int row = f >> 3, k16l = f & 7;
    const float4* p = (const float4*)(srow + (size_t)row * D + c * 128 + k16l * 16);
    float qm = qmul[t * 128 + row];
    union { i32x4 v; signed char b[16]; } pk;
#pragma unroll
    for (int u = 0; u < 4; ++u) {
      float4 v = p[u];
      float vv[4] = {v.x, v.y, v.z, v.w};
#pragma unroll
      for (int e = 0; e < 4; ++e) {
        int q = __float2int_rn(vv[e] * qm);
        q = q > 127 ? 127 : (q < -127 ? -127 : q);
        pk.b[u * 4 + e] = (signed char)q;
      }
    }
    *(i32x4*)&tile[row][k16l * 16] = pk.v;
  }
  __syncthreads();
#pragma unroll
  for (int j = 0; j < 4; ++j) {
    int g = tid + j * 256;               // out granule: row = g&127, k16l = g>>7
    int row = g & 127, k16l = g >> 7;
    i32x4 v = *(const i32x4*)&tile[row][k16l * 16];
    *(i32x4*)(dbase + (((size_t)(c * 8 + k16l) * 128 + row) * 16)) = v;
  }
}

// ---- 3. 128x128-tile BK=64 i8 GEMM, co-resident A-tile sharing --------------
// 256 threads = 4 waves (wr, wc in {0,1}). Wave tile: 64 rows x 64 codes.
// Swapped mfma_i32_16x16x64_i8(b, a): acc[nc][m][q] -> code = ct*128 + wc*64 +
// nc*16 + lh*4 + q, row = mt*128 + wr*64 + m*16 + lr.
__global__ __launch_bounds__(256, 4)
void vq_gemm_i8s(const char* __restrict__ Apack, const char* __restrict__ Bpack,
                 const float* __restrict__ e_sq,
                 const float* __restrict__ sval_x, const float* __restrict__ sval_e,
                 ulonglong2* __restrict__ cand2) {
  __shared__ char As[2][512 * 16];   // 2 x 8 KB
  __shared__ char Bs[2][512 * 16];   // 2 x 8 KB

  const int tid = threadIdx.x;
  const int w = tid >> 6, l = tid & 63;
  const int wr = w >> 1, wc = w & 1;
  const int lr = l & 15, lh = l >> 4;

  // CO-RESIDENCY map: bids b, b+1024, ... land on ~the same CU; give them the
  // same mt so they share one A-tile (L1/L2-hot A staging). Bijective:
  // bid in [0,8192) -> (mt in [0,128), ct in [0,64)).
  const int bid = blockIdx.x;
  const int slot = bid & 1023;
  const int mt = slot >> 3;                 // shared by 8 co-resident blocks
  const int ct = (slot & 7) + ((bid >> 10) << 3);

  const char* Abase = Apack + (size_t)mt * TILEB;
  const char* Bbase = Bpack + (size_t)ct * TILEB;

  i32x4 acc[4][4] = {};

#define STAGE(buf, t)                                                          \
  do {                                                                         \
    _Pragma("unroll")                                                          \
    for (int i = 0; i < 2; ++i) {                                              \
      const int g = tid + i * 256;                                             \
      gload16(Abase + ((size_t)(t) * 512 + g) * 16, As[(buf)] + (size_t)g * 16); \
      gload16(Bbase + ((size_t)(t) * 512 + g) * 16, Bs[(buf)] + (size_t)g * 16); \
    }                                                                          \
  } while (0)

#define COMPUTE(buf)                                                           \
  do {                                                                         \
    const i32x4* Ag = (const i32x4*)As[(buf)];                                 \
    const i32x4* Bg = (const i32x4*)Bs[(buf)];                                 \
    i32x4 a[4], b[4];                                                          \
    _Pragma("unroll")                                                          \
    for (int nc = 0; nc < 4; ++nc) b[nc] = Bg[lh * 128 + wc * 64 + nc * 16 + lr]; \
    _Pragma("unroll")                                                          \
    for (int m = 0; m < 4; ++m)   a[m] = Ag[lh * 128 + wr * 64 + m * 16 + lr];    \
    _Pragma("unroll")                                                          \
    for (int nc = 0; nc < 4; ++nc)                                             \
      _Pragma("unroll")                                                        \
      for (int m = 0; m < 4; ++m)                                              \
        acc[nc][m] = __builtin_amdgcn_mfma_i32_16x16x64_i8(b[nc], a[m],        \
                                                           acc[nc][m], 0, 0, 0); \
  } while (0)

  STAGE(0, 0);
  __syncthreads();
#pragma unroll 1
  for (int t = 0; t < NSTEP - 1; ++t) {
    const int cur = t & 1;
    STAGE(cur ^ 1, t + 1);       // prefetch issued before compute
    COMPUTE(cur);
    __syncthreads();             // one barrier per step
  }
  COMPUTE((NSTEP - 1) & 1);
#undef STAGE
#undef COMPUTE

  // ---- epilogue: per-row top-2 keys over this wave's 64-code strip ----
  const int col0 = ct * 128 + wc * 64;
  float es[4][4], sev[4][4], sxv[4];
#pragma unroll
  for (int nc = 0; nc < 4; ++nc) {
    float4 e4 = *(const float4*)&e_sq[col0 + nc * 16 + lh * 4];
    float4 s4 = *(const float4*)&sval_e[col0 + nc * 16 + lh * 4];
    es[nc][0] = e4.x; es[nc][1] = e4.y; es[nc][2] = e4.z; es[nc][3] = e4.w;
    sev[nc][0] = s4.x; sev[nc][1] = s4.y; sev[nc][2] = s4.z; sev[nc][3] = s4.w;
  }
#pragma unroll
  for (int m = 0; m < 4; ++m)
    sxv[m] = sval_x[mt * 128 + wr * 64 + m * 16 + lr];

#pragma unroll
  for (int m = 0; m < 4; ++m) {
    unsigned long long k1 = KMAX, k2 = KMAX;
    const float sx2 = 2.0f * sxv[m];
#pragma unroll
    for (int nc = 0; nc < 4; ++nc)
#pragma unroll
      for (int q = 0; q < 4; ++q) {
        int code = col0 + nc * 16 + lh * 4 + q;
        float sc = es[nc][q] - sx2 * sev[nc][q] * (float)acc[nc][m][q];
        kins2(score_key(sc, code), k1, k2);
      }
#pragma unroll
    for (int s = 16; s <= 32; s <<= 1) {     // reduce over lh (4 lanes per lr)
      unsigned long long o1 = __shfl_xor(k1, s, 64);
      unsigned long long o2 = __shfl_xor(k2, s, 64);
      kins2(o1, k1, k2);
      kins2(o2, k1, k2);
    }
    if (lh == 0) {
      int gRow = mt * 128 + wr * 64 + m * 16 + lr;
      cand2[(size_t)gRow * 128 + ct * 2 + wc] = make_ulonglong2(k1, k2);
    }
  }
}

// ---- 4. global top-4 over 256 keys/row, exact f32 rescore, gather -----------
__global__ __launch_bounds__(256)
void vq_merge4(const float* __restrict__ x, const float* __restrict__ cb,
               const float* __restrict__ values, const float* __restrict__ e_sq,
               const ulonglong2* __restrict__ cand2, float* __restrict__ out) {
  int row = blockIdx.x * 4 + (threadIdx.x >> 6);
  int l = threadIdx.x & 63;

  unsigned long long k0 = KMAX, k1 = KMAX, k2 = KMAX, k3 = KMAX;
  const ulonglong2* base = cand2 + (size_t)row * 128;
#pragma unroll
  for (int u = 0; u < 2; ++u) {
    ulonglong2 e = base[l + 64 * u];
    kins4(e.x, k0, k1, k2, k3);
    kins4(e.y, k0, k1, k2, k3);
  }
#pragma unroll
  for (int s = 1; s < 64; s <<= 1) {
    unsigned long long o0 = __shfl_xor(k0, s, 64), o1 = __shfl_xor(k1, s, 64);
    unsigned long long o2 = __shfl_xor(k2, s, 64), o3 = __shfl_xor(k3, s, 64);
    kins4(o0, k0, k1, k2, k3); kins4(o1, k0, k1, k2, k3);
    kins4(o2, k0, k1, k2, k3); kins4(o3, k0, k1, k2, k3);
  }
  int i0 = (int)(k0 & 8191), i1 = (int)(k1 & 8191);
  int i2 = (int)(k2 & 8191), i3 = (int)(k3 & 8191);

  // exact f32 rescore (deterministic order)
  const float4* xr = (const float4*)(x + (size_t)row * D);
  const float4* c0 = (const float4*)(cb + (size_t)i0 * D);
  const float4* c1 = (const float4*)(cb + (size_t)i1 * D);
  const float4* c2 = (const float4*)(cb + (size_t)i2 * D);
  const float4* c3 = (const float4*)(cb + (size_t)i3 * D);
  float xsq = 0.f, t0 = 0.f, t1 = 0.f, t2 = 0.f, t3 = 0.f;
#pragma unroll
  for (int u = 0; u < 2; ++u) {
    float4 xv = xr[l + 64 * u];
    float4 a = c0[l + 64 * u], b = c1[l + 64 * u];
    float4 c = c2[l + 64 * u], e = c3[l + 64 * u];
    xsq += xv.x * xv.x + xv.y * xv.y + xv.z * xv.z + xv.w * xv.w;
    t0 += xv.x * a.x + xv.y * a.y + xv.z * a.z + xv.w * a.w;
    t1 += xv.x * b.x + xv.y * b.y + xv.z * b.z + xv.w * b.w;
    t2 += xv.x * c.x + xv.y * c.y + xv.z * c.z + xv.w * c.w;
    t3 += xv.x * e.x + xv.y * e.y + xv.z * e.z + xv.w * e.w;
  }
#pragma unroll
  for (int s = 1; s < 64; s <<= 1) {
    xsq += __shfl_xor(xsq, s, 64);
    t0 += __shfl_xor(t0, s, 64); t1 += __shfl_xor(t1, s, 64);
    t2 += __shfl_xor(t2, s, 64); t3 += __shfl_xor(t3, s, 64);
  }
  float D0 = xsq - 2.0f * t0 + e_sq[i0];
  float D1 = xsq - 2.0f * t1 + e_sq[i1];
  float D2 = xsq - 2.0f * t2 + e_sq[i2];
  float D3 = xsq - 2.0f * t3 + e_sq[i3];
  float bdist = D0; int best = i0;
  if (D1 < bdist || (D1 == bdist && i1 < best)) { bdist = D1; best = i1; }
  if (D2 < bdist || (D2 == bdist && i2 < best)) { bdist = D2; best = i2; }
  if (D3 < bdist || (D3 == bdist && i3 < best)) { bdist = D3; best = i3; }

  const float4* vsrc = (const float4*)(values + (size_t)best * D);
  float4* dst = (float4*)(out + (size_t)row * D);
  dst[l] = vsrc[l];
  dst[l + 64] = vsrc[l + 64];
}

// ============================================================================
extern "C" void kernel_launch(void* const* d_in, const int* in_sizes, int n_in,
                              void* d_out, int out_size, void* d_ws, size_t ws_size,
                              hipStream_t stream) {
  const float* x      = (const float*)d_in[0];
  const float* cb     = (const float*)d_in[1];
  const float* values = (const float*)d_in[2];
  float* out = (float*)d_out;

  const size_t A_BYTES = (size_t)M * D;               // 8 MB (i8)
  const size_t B_BYTES = (size_t)NCODE * D;           // 4 MB (i8)
  const size_t C_BYTES = (size_t)M * 128 * 16;        // 32 MB (key pairs)

  char* base = (char*)d_ws;
  char* Apack = base;
  char* Bpack = base + A_BYTES;
  ulonglong2* cand2 = (ulonglong2*)(base + A_BYTES + B_BYTES);
  float* qmul_x = (float*)(base + A_BYTES + B_BYTES + C_BYTES);
  float* sval_x = qmul_x + M;
  float* qmul_e = sval_x + M;
  float* sval_e = qmul_e + NCODE;
  float* e_sq   = sval_e + NCODE;

  scales_kernel<<<(M + NCODE) / 4, 256, 0, stream>>>(
      x, cb, qmul_x, sval_x, qmul_e, sval_e, e_sq);
  prep_i8t<<<(M / 128) * 4, 256, 0, stream>>>(x, qmul_x, Apack);
  prep_i8t<<<(NCODE / 128) * 4, 256, 0, stream>>>(cb, qmul_e, Bpack);
  vq_gemm_i8s<<<(M / 128) * (NCODE / 128), 256, 0, stream>>>(
      Apack, Bpack, e_sq, sval_x, sval_e, cand2);
  vq_merge4<<<M / 4, 256, 0, stream>>>(x, cb, values, e_sq, cand2, out);
}